// Round 8
// baseline (190.189 us; speedup 1.0000x reference)
//
#include <hip/hip_runtime.h>
#include <hip/hip_bf16.h>

#define NB 2048
#define LL 512
#define LS 64
#define LT (LL + LS)   // 576 rows per batch
#define D 64
#define BLOCK 256
#define NWAVE 4
#define NIT (LT / 32)  // 18 iterations (32 row-groups per block)
#define NUM_ITEMS 100000
#define TABLE_ELEMS (NUM_ITEMS * D)           // 6,400,000
#define TABLE_BYTES ((size_t)TABLE_ELEMS * 2) // 12.8 MB as bf16

typedef unsigned short ushort_t;

__device__ __forceinline__ float u2f(unsigned int bits) {
    union { unsigned int i; float f; } c; c.i = bits; return c.f;
}

__device__ __forceinline__ ushort_t f2bf(float f) {
    union { float f; unsigned int u; } c; c.f = f;
    unsigned int u = c.u;
    unsigned int r = (u + 0x7fffu + ((u >> 16) & 1u)) >> 16;   // RTNE
    return (ushort_t)r;
}

__device__ __forceinline__ unsigned int pack2(float lo, float hi) {
    return (unsigned int)f2bf(lo) | ((unsigned int)f2bf(hi) << 16);
}

// fp32 emb -> bf16 table (one uint4 = 8 bf16 per thread)
__global__ void __launch_bounds__(256) cvt_kernel(const float* __restrict__ emb,
                                                  uint4* __restrict__ dst)
{
    const size_t i = (size_t)blockIdx.x * 256 + threadIdx.x;   // < TABLE_ELEMS/8
    const float4* src = (const float4*)emb + 2 * i;
    const float4 a = src[0];
    const float4 b = src[1];
    uint4 r;
    r.x = pack2(a.x, a.y);
    r.y = pack2(a.z, a.w);
    r.z = pack2(b.x, b.y);
    r.w = pack2(b.z, b.w);
    dst[i] = r;
}

// unpack 8 bf16 (as uint4) -> 8 floats
__device__ __forceinline__ void unpack8(uint4 u, float* f) {
    f[0] = u2f(u.x << 16);
    f[1] = u2f(u.x & 0xffff0000u);
    f[2] = u2f(u.y << 16);
    f[3] = u2f(u.y & 0xffff0000u);
    f[4] = u2f(u.z << 16);
    f[5] = u2f(u.z & 0xffff0000u);
    f[6] = u2f(u.w << 16);
    f[7] = u2f(u.w & 0xffff0000u);
}

__device__ __forceinline__ float softplus_f(float x) {
    return fmaxf(x, 0.f) + log1pf(expf(-fabsf(x)));
}

// Online-softmax: add one element (logit, weight=sim) to state (m, n, d)
__device__ __forceinline__ void oupd(float& m, float& n, float& d,
                                     float logit, float sim) {
    float M = fmaxf(m, logit);
    float a = __expf(m - M);        // 0 when m = -1e30
    float e = __expf(logit - M);
    n = fmaf(n, a, e * sim);
    d = fmaf(d, a, e);
    m = M;
}

// Merge two online-softmax states
__device__ __forceinline__ void omerge(float& m, float& n, float& d,
                                       float m2, float n2, float d2) {
    float M = fmaxf(m, m2);
    float a = __expf(m - M), bb = __expf(m2 - M);
    n = n * a + n2 * bb;
    d = d * a + d2 * bb;
    m = M;
}

__device__ __forceinline__ void shfl_merge(float& m, float& n, float& d, int off) {
    float m2 = __shfl_xor(m, off);
    float n2 = __shfl_xor(n, off);
    float d2 = __shfl_xor(d, off);
    omerge(m, n, d, m2, n2, d2);
}

template <bool USE_BF16>
__global__ void __launch_bounds__(BLOCK, 8) lic_kernel(
    const int* __restrict__ items_long, const int* __restrict__ dts_long,
    const int* __restrict__ items_short, const int* __restrict__ dts_short,
    const int* __restrict__ pos_items, const int* __restrict__ neg_items,
    const float* __restrict__ emb, const ushort_t* __restrict__ tabh,
    const float* __restrict__ gate_g, const float* __restrict__ gate_e,
    const float* __restrict__ raw_tau_g, const float* __restrict__ raw_tau_e,
    const float* __restrict__ fuse_logits,
    float* __restrict__ out)
{
    __shared__ int   s_items[LT];
    __shared__ float s_gate[LT];          // gate * inv_tau (pre-scaled)
    __shared__ float s_red[NWAVE * 12];

    const int b = blockIdx.x;
    const int tid = threadIdx.x;
    const int lane = tid & 63;
    const int wave = tid >> 6;
    const int sub = lane & 7;        // 16B chunk within row
    const int rloc = lane >> 3;      // row-group within wave

    const float tau_g = softplus_f(raw_tau_g[0]) + 1e-6f;
    const float tau_e = softplus_f(raw_tau_e[0]) + 1e-6f;
    const float inv_tau_g = 1.f / tau_g;
    const float inv_tau_e = 1.f / tau_e;
    const float lam = 1.f / (1.f + expf(fuse_logits[1] - fuse_logits[0]));

    // ---- stage all 576 indices + prescaled gates into LDS (coalesced) ----
    {
        int2 it = ((const int2*)(items_long + (size_t)b * LL))[tid];
        int2 dt = ((const int2*)(dts_long  + (size_t)b * LL))[tid];
        s_items[2 * tid]     = it.x;
        s_items[2 * tid + 1] = it.y;
        s_gate[2 * tid]      = gate_g[dt.x] * inv_tau_g;   // 512B table: L1-resident
        s_gate[2 * tid + 1]  = gate_g[dt.y] * inv_tau_g;
        if (tid < LS / 2) {
            int2 its = ((const int2*)(items_short + (size_t)b * LS))[tid];
            int2 dts = ((const int2*)(dts_short  + (size_t)b * LS))[tid];
            s_items[LL + 2 * tid]     = its.x;
            s_items[LL + 2 * tid + 1] = its.y;
            s_gate[LL + 2 * tid]      = gate_e[dts.x] * inv_tau_e;
            s_gate[LL + 2 * tid + 1]  = gate_e[dts.y] * inv_tau_e;
        }
    }

    // q fragments (fp32): lane holds elements [sub*8, sub*8+8)
    float qp[8], qn[8];
    {
        const int pi = pos_items[b];
        const int ni = neg_items[b];
        const float* pp = emb + (size_t)pi * D + sub * 8;
        const float* pn = emb + (size_t)ni * D + sub * 8;
        float4 a0 = *(const float4*)(pp);
        float4 a1 = *(const float4*)(pp + 4);
        float4 b0 = *(const float4*)(pn);
        float4 b1 = *(const float4*)(pn + 4);
        qp[0]=a0.x; qp[1]=a0.y; qp[2]=a0.z; qp[3]=a0.w;
        qp[4]=a1.x; qp[5]=a1.y; qp[6]=a1.z; qp[7]=a1.w;
        qn[0]=b0.x; qn[1]=b0.y; qn[2]=b0.z; qn[3]=b0.w;
        qn[4]=b1.x; qn[5]=b1.y; qn[6]=b1.z; qn[7]=b1.w;
    }
    __syncthreads();   // staging complete

    // online-softmax states: 0=long/pos 1=long/neg 2=short/pos 3=short/neg
    float m0=-1e30f, n0=0.f, d0=0.f;
    float m1=-1e30f, n1=0.f, d1=0.f;
    float m2=-1e30f, n2=0.f, d2=0.f;
    float m3=-1e30f, n3=0.f, d3=0.f;

    const int start = wave * 8 + rloc;   // 0..31; rows: start + 32*i

    if (USE_BF16) {
        const uint4* __restrict__ tab = (const uint4*)tabh;

        // CONSUME(i, reg): dot row (start+32*i) against qp/qn, update state.
        // All 8 lanes of the group end with identical sp/sn (full xor butterfly).
#define CONSUME(I, U)                                                        \
        do {                                                                 \
            float kf[8];                                                     \
            unpack8((U), kf);                                                \
            float sp = kf[0] * qp[0], sn = kf[0] * qn[0];                    \
            _Pragma("unroll")                                                \
            for (int j = 1; j < 8; ++j) {                                    \
                sp = fmaf(kf[j], qp[j], sp);                                 \
                sn = fmaf(kf[j], qn[j], sn);                                 \
            }                                                                \
            sp += __shfl_xor(sp, 1); sn += __shfl_xor(sn, 1);                \
            sp += __shfl_xor(sp, 2); sn += __shfl_xor(sn, 2);                \
            sp += __shfl_xor(sp, 4); sn += __shfl_xor(sn, 4);                \
            const float gs = s_gate[start + 32 * (I)];                       \
            if ((I) < 16) {                                                  \
                oupd(m0, n0, d0, sp * gs, sp);                               \
                oupd(m1, n1, d1, sn * gs, sn);                               \
            } else {                                                         \
                oupd(m2, n2, d2, sp * gs, sp);                               \
                oupd(m3, n3, d3, sn * gs, sn);                               \
            }                                                                \
        } while (0)

        // LD(i): row load; tail refills clamp to row `start` (L1-hit, ~free),
        // keeping every store to A..D unconditional -> stays in VGPRs.
#define LD(I) tab[(size_t)s_items[((I) < NIT) ? (start + 32 * (I)) : start] * 8 + sub]

        uint4 A = LD(0);
        uint4 Bv = LD(1);
        uint4 C = LD(2);
        uint4 Dv = LD(3);

        CONSUME(0, A);   A  = LD(4);
        CONSUME(1, Bv);  Bv = LD(5);
        CONSUME(2, C);   C  = LD(6);
        CONSUME(3, Dv);  Dv = LD(7);
        CONSUME(4, A);   A  = LD(8);
        CONSUME(5, Bv);  Bv = LD(9);
        CONSUME(6, C);   C  = LD(10);
        CONSUME(7, Dv);  Dv = LD(11);
        CONSUME(8, A);   A  = LD(12);
        CONSUME(9, Bv);  Bv = LD(13);
        CONSUME(10, C);  C  = LD(14);
        CONSUME(11, Dv); Dv = LD(15);
        CONSUME(12, A);  A  = LD(16);
        CONSUME(13, Bv); Bv = LD(17);
        CONSUME(14, C);  C  = LD(18);   // clamped dummy
        CONSUME(15, Dv); Dv = LD(19);   // clamped dummy
        CONSUME(16, A);
        CONSUME(17, Bv);
        (void)C; (void)Dv;
#undef LD
#undef CONSUME
    } else {
        // fp32 fallback (ws too small) — simple loop
        for (int i = 0; i < NIT; ++i) {
            const int row = start + 32 * i;
            const float* rp = emb + (size_t)s_items[row] * D + sub * 8;
            const float4 u0 = *(const float4*)(rp);
            const float4 u1 = *(const float4*)(rp + 4);
            float kf[8] = {u0.x,u0.y,u0.z,u0.w,u1.x,u1.y,u1.z,u1.w};
            float sp = kf[0] * qp[0], sn = kf[0] * qn[0];
            for (int j = 1; j < 8; ++j) {
                sp = fmaf(kf[j], qp[j], sp);
                sn = fmaf(kf[j], qn[j], sn);
            }
            sp += __shfl_xor(sp, 1); sn += __shfl_xor(sn, 1);
            sp += __shfl_xor(sp, 2); sn += __shfl_xor(sn, 2);
            sp += __shfl_xor(sp, 4); sn += __shfl_xor(sn, 4);
            const float gs = s_gate[row];
            if (row < LL) {
                oupd(m0, n0, d0, sp * gs, sp);
                oupd(m1, n1, d1, sn * gs, sn);
            } else {
                oupd(m2, n2, d2, sp * gs, sp);
                oupd(m3, n3, d3, sn * gs, sn);
            }
        }
    }

    // merge the 8 row-groups within each wave (states replicated across 8 lanes)
#pragma unroll
    for (int off = 8; off <= 32; off <<= 1) {
        shfl_merge(m0, n0, d0, off);
        shfl_merge(m1, n1, d1, off);
        shfl_merge(m2, n2, d2, off);
        shfl_merge(m3, n3, d3, off);
    }
    if (lane == 0) {
        float* r = s_red + wave * 12;
        r[0]=m0; r[1]=n0; r[2]=d0;
        r[3]=m1; r[4]=n1; r[5]=d1;
        r[6]=m2; r[7]=n2; r[8]=d2;
        r[9]=m3; r[10]=n3; r[11]=d3;
    }
    __syncthreads();

    if (tid == 0) {
        float M0=s_red[0], N0=s_red[1], D0=s_red[2];
        float M1=s_red[3], N1=s_red[4], D1=s_red[5];
        float M2=s_red[6], N2=s_red[7], D2=s_red[8];
        float M3=s_red[9], N3=s_red[10], D3=s_red[11];
#pragma unroll
        for (int w = 1; w < NWAVE; ++w) {
            const float* r = s_red + w * 12;
            omerge(M0, N0, D0, r[0], r[1], r[2]);
            omerge(M1, N1, D1, r[3], r[4], r[5]);
            omerge(M2, N2, D2, r[6], r[7], r[8]);
            omerge(M3, N3, D3, r[9], r[10], r[11]);
        }
        const float cgx = N0 / D0, cgy = N1 / D1;
        const float cex = N2 / D2, cey = N3 / D3;
        out[b]      = lam * cgx + (1.f - lam) * cex;
        out[NB + b] = lam * cgy + (1.f - lam) * cey;
        if (b == 0) {
            out[2 * NB]     = lam;
            out[2 * NB + 1] = tau_g;
            out[2 * NB + 2] = tau_e;
        }
    }
}

extern "C" void kernel_launch(void* const* d_in, const int* in_sizes, int n_in,
                              void* d_out, int out_size, void* d_ws, size_t ws_size,
                              hipStream_t stream) {
    const int* items_long  = (const int*)d_in[0];
    const int* dts_long    = (const int*)d_in[1];
    const int* items_short = (const int*)d_in[3];
    const int* dts_short   = (const int*)d_in[4];
    const int* pos_items   = (const int*)d_in[6];
    const int* neg_items   = (const int*)d_in[7];
    const float* emb       = (const float*)d_in[8];
    const float* gate_g    = (const float*)d_in[9];
    const float* gate_e    = (const float*)d_in[10];
    const float* raw_tau_g = (const float*)d_in[11];
    const float* raw_tau_e = (const float*)d_in[12];
    const float* fuse      = (const float*)d_in[13];
    float* out = (float*)d_out;

    if (ws_size >= TABLE_BYTES) {
        const ushort_t* tabh = (const ushort_t*)d_ws;
        cvt_kernel<<<TABLE_ELEMS / 8 / 256, 256, 0, stream>>>(emb, (uint4*)d_ws);
        lic_kernel<true><<<NB, BLOCK, 0, stream>>>(
            items_long, dts_long, items_short, dts_short,
            pos_items, neg_items, emb, tabh, gate_g, gate_e,
            raw_tau_g, raw_tau_e, fuse, out);
    } else {
        lic_kernel<false><<<NB, BLOCK, 0, stream>>>(
            items_long, dts_long, items_short, dts_short,
            pos_items, neg_items, emb, (const ushort_t*)nullptr, gate_g, gate_e,
            raw_tau_g, raw_tau_e, fuse, out);
    }
}

// Round 9
// 127.543 us; speedup vs baseline: 1.4912x; 1.4912x over previous
//
#include <hip/hip_runtime.h>
#include <hip/hip_bf16.h>

#define NB 2048
#define LL 512
#define LS 64
#define LT (LL + LS)   // 576 rows per batch
#define D 64
#define BLOCK 256
#define NWAVE 4
#define NIT (LT / 32)  // 18 row-groups of 32 per block
#define NUM_ITEMS 100000
#define TABLE_ELEMS (NUM_ITEMS * D)           // 6,400,000
#define TABLE_BYTES ((size_t)TABLE_ELEMS * 2) // 12.8 MB as bf16

typedef unsigned short ushort_t;

__device__ __forceinline__ float u2f(unsigned int bits) {
    union { unsigned int i; float f; } c; c.i = bits; return c.f;
}

__device__ __forceinline__ ushort_t f2bf(float f) {
    union { float f; unsigned int u; } c; c.f = f;
    unsigned int u = c.u;
    unsigned int r = (u + 0x7fffu + ((u >> 16) & 1u)) >> 16;   // RTNE
    return (ushort_t)r;
}

__device__ __forceinline__ unsigned int pack2(float lo, float hi) {
    return (unsigned int)f2bf(lo) | ((unsigned int)f2bf(hi) << 16);
}

// fp32 emb -> bf16 table (one uint4 = 8 bf16 per thread)
__global__ void __launch_bounds__(256) cvt_kernel(const float* __restrict__ emb,
                                                  uint4* __restrict__ dst)
{
    const size_t i = (size_t)blockIdx.x * 256 + threadIdx.x;   // < TABLE_ELEMS/8
    const float4* src = (const float4*)emb + 2 * i;
    const float4 a = src[0];
    const float4 b = src[1];
    uint4 r;
    r.x = pack2(a.x, a.y);
    r.y = pack2(a.z, a.w);
    r.z = pack2(b.x, b.y);
    r.w = pack2(b.z, b.w);
    dst[i] = r;
}

// 8 named scalars — no arrays, no dynamic indexing, SROA-proof.
struct F8 { float a, b, c, d, e, f, g, h; };

__device__ __forceinline__ F8 unpack8(uint4 u) {
    F8 r;
    r.a = u2f(u.x << 16); r.b = u2f(u.x & 0xffff0000u);
    r.c = u2f(u.y << 16); r.d = u2f(u.y & 0xffff0000u);
    r.e = u2f(u.z << 16); r.f = u2f(u.z & 0xffff0000u);
    r.g = u2f(u.w << 16); r.h = u2f(u.w & 0xffff0000u);
    return r;
}

// dual dot-product: sp = k.qp, sn = k.qn (straight-line, 16 fma)
__device__ __forceinline__ void dot2(const F8& k, const F8& qp, const F8& qn,
                                     float& sp, float& sn) {
    sp = k.a * qp.a;            sn = k.a * qn.a;
    sp = fmaf(k.b, qp.b, sp);   sn = fmaf(k.b, qn.b, sn);
    sp = fmaf(k.c, qp.c, sp);   sn = fmaf(k.c, qn.c, sn);
    sp = fmaf(k.d, qp.d, sp);   sn = fmaf(k.d, qn.d, sn);
    sp = fmaf(k.e, qp.e, sp);   sn = fmaf(k.e, qn.e, sn);
    sp = fmaf(k.f, qp.f, sp);   sn = fmaf(k.f, qn.f, sn);
    sp = fmaf(k.g, qp.g, sp);   sn = fmaf(k.g, qn.g, sn);
    sp = fmaf(k.h, qp.h, sp);   sn = fmaf(k.h, qn.h, sn);
}

__device__ __forceinline__ float softplus_f(float x) {
    return fmaxf(x, 0.f) + log1pf(expf(-fabsf(x)));
}

// Online-softmax: add one element (logit, weight=sim) to state (m, n, d)
__device__ __forceinline__ void oupd(float& m, float& n, float& d,
                                     float logit, float sim) {
    float M = fmaxf(m, logit);
    float a = __expf(m - M);        // 0 when m = -1e30
    float e = __expf(logit - M);
    n = fmaf(n, a, e * sim);
    d = fmaf(d, a, e);
    m = M;
}

__device__ __forceinline__ void omerge(float& m, float& n, float& d,
                                       float m2, float n2, float d2) {
    float M = fmaxf(m, m2);
    float a = __expf(m - M), bb = __expf(m2 - M);
    n = n * a + n2 * bb;
    d = d * a + d2 * bb;
    m = M;
}

__device__ __forceinline__ void shfl_merge(float& m, float& n, float& d, int off) {
    float m2 = __shfl_xor(m, off);
    float n2 = __shfl_xor(n, off);
    float d2 = __shfl_xor(d, off);
    omerge(m, n, d, m2, n2, d2);
}

template <bool USE_BF16>
__global__ void __launch_bounds__(BLOCK, 4) lic_kernel(   // 4 waves/EU -> 128 VGPR cap
    const int* __restrict__ items_long, const int* __restrict__ dts_long,
    const int* __restrict__ items_short, const int* __restrict__ dts_short,
    const int* __restrict__ pos_items, const int* __restrict__ neg_items,
    const float* __restrict__ emb, const ushort_t* __restrict__ tabh,
    const float* __restrict__ gate_g, const float* __restrict__ gate_e,
    const float* __restrict__ raw_tau_g, const float* __restrict__ raw_tau_e,
    const float* __restrict__ fuse_logits,
    float* __restrict__ out)
{
    __shared__ int   s_items[LT];
    __shared__ float s_gate[LT];          // gate * inv_tau (pre-scaled)
    __shared__ float s_red[NWAVE * 12];

    const int b = blockIdx.x;
    const int tid = threadIdx.x;
    const int lane = tid & 63;
    const int wave = tid >> 6;
    const int sub = lane & 7;        // 16B chunk within row
    const int rloc = lane >> 3;      // row-group within wave

    const float tau_g = softplus_f(raw_tau_g[0]) + 1e-6f;
    const float tau_e = softplus_f(raw_tau_e[0]) + 1e-6f;
    const float inv_tau_g = 1.f / tau_g;
    const float inv_tau_e = 1.f / tau_e;
    const float lam = 1.f / (1.f + expf(fuse_logits[1] - fuse_logits[0]));

    // ---- stage all 576 indices + prescaled gates into LDS (coalesced) ----
    {
        int2 it = ((const int2*)(items_long + (size_t)b * LL))[tid];
        int2 dt = ((const int2*)(dts_long  + (size_t)b * LL))[tid];
        s_items[2 * tid]     = it.x;
        s_items[2 * tid + 1] = it.y;
        s_gate[2 * tid]      = gate_g[dt.x] * inv_tau_g;   // 512B table: L1-resident
        s_gate[2 * tid + 1]  = gate_g[dt.y] * inv_tau_g;
        if (tid < LS / 2) {
            int2 its = ((const int2*)(items_short + (size_t)b * LS))[tid];
            int2 dts = ((const int2*)(dts_short  + (size_t)b * LS))[tid];
            s_items[LL + 2 * tid]     = its.x;
            s_items[LL + 2 * tid + 1] = its.y;
            s_gate[LL + 2 * tid]      = gate_e[dts.x] * inv_tau_e;
            s_gate[LL + 2 * tid + 1]  = gate_e[dts.y] * inv_tau_e;
        }
    }

    // q fragments (fp32): lane holds elements [sub*8, sub*8+8)
    F8 qp, qn;
    {
        const int pi = pos_items[b];
        const int ni = neg_items[b];
        const float* pp = emb + (size_t)pi * D + sub * 8;
        const float* pn = emb + (size_t)ni * D + sub * 8;
        float4 a0 = *(const float4*)(pp);
        float4 a1 = *(const float4*)(pp + 4);
        float4 b0 = *(const float4*)(pn);
        float4 b1 = *(const float4*)(pn + 4);
        qp.a=a0.x; qp.b=a0.y; qp.c=a0.z; qp.d=a0.w;
        qp.e=a1.x; qp.f=a1.y; qp.g=a1.z; qp.h=a1.w;
        qn.a=b0.x; qn.b=b0.y; qn.c=b0.z; qn.d=b0.w;
        qn.e=b1.x; qn.f=b1.y; qn.g=b1.z; qn.h=b1.w;
    }
    __syncthreads();   // staging complete

    // online-softmax states: 0=long/pos 1=long/neg 2=short/pos 3=short/neg
    float m0=-1e30f, n0=0.f, d0=0.f;
    float m1=-1e30f, n1=0.f, d1=0.f;
    float m2=-1e30f, n2=0.f, d2=0.f;
    float m3=-1e30f, n3=0.f, d3=0.f;

    const int start = wave * 8 + rloc;   // 0..31; rows: start + 32*i

    if (USE_BF16) {
        const uint4* __restrict__ tab = (const uint4*)tabh;

#define CONSUME(I, U)                                                        \
        do {                                                                 \
            F8 k = unpack8(U);                                               \
            float sp, sn;                                                    \
            dot2(k, qp, qn, sp, sn);                                         \
            sp += __shfl_xor(sp, 1); sn += __shfl_xor(sn, 1);                \
            sp += __shfl_xor(sp, 2); sn += __shfl_xor(sn, 2);                \
            sp += __shfl_xor(sp, 4); sn += __shfl_xor(sn, 4);                \
            const float gs = s_gate[start + 32 * (I)];                       \
            if ((I) < 16) {                                                  \
                oupd(m0, n0, d0, sp * gs, sp);                               \
                oupd(m1, n1, d1, sn * gs, sn);                               \
            } else {                                                         \
                oupd(m2, n2, d2, sp * gs, sp);                               \
                oupd(m3, n3, d3, sn * gs, sn);                               \
            }                                                                \
        } while (0)

#define LD(I) tab[(size_t)s_items[start + 32 * (I)] * 8 + sub]

        uint4 A  = LD(0);
        uint4 Bv = LD(1);
        uint4 C  = LD(2);
        uint4 Dv = LD(3);

        CONSUME(0, A);   A  = LD(4);
        CONSUME(1, Bv);  Bv = LD(5);
        CONSUME(2, C);   C  = LD(6);
        CONSUME(3, Dv);  Dv = LD(7);
        CONSUME(4, A);   A  = LD(8);
        CONSUME(5, Bv);  Bv = LD(9);
        CONSUME(6, C);   C  = LD(10);
        CONSUME(7, Dv);  Dv = LD(11);
        CONSUME(8, A);   A  = LD(12);
        CONSUME(9, Bv);  Bv = LD(13);
        CONSUME(10, C);  C  = LD(14);
        CONSUME(11, Dv); Dv = LD(15);
        CONSUME(12, A);  A  = LD(16);
        CONSUME(13, Bv); Bv = LD(17);
        CONSUME(14, C);
        CONSUME(15, Dv);
        CONSUME(16, A);
        CONSUME(17, Bv);
#undef LD
#undef CONSUME
    } else {
        // fp32 fallback (ws too small) — simple loop, struct-scalar body
        for (int i = 0; i < NIT; ++i) {
            const int row = start + 32 * i;
            const float* rp = emb + (size_t)s_items[row] * D + sub * 8;
            const float4 u0 = *(const float4*)(rp);
            const float4 u1 = *(const float4*)(rp + 4);
            F8 k;
            k.a=u0.x; k.b=u0.y; k.c=u0.z; k.d=u0.w;
            k.e=u1.x; k.f=u1.y; k.g=u1.z; k.h=u1.w;
            float sp, sn;
            dot2(k, qp, qn, sp, sn);
            sp += __shfl_xor(sp, 1); sn += __shfl_xor(sn, 1);
            sp += __shfl_xor(sp, 2); sn += __shfl_xor(sn, 2);
            sp += __shfl_xor(sp, 4); sn += __shfl_xor(sn, 4);
            const float gs = s_gate[row];
            if (row < LL) {
                oupd(m0, n0, d0, sp * gs, sp);
                oupd(m1, n1, d1, sn * gs, sn);
            } else {
                oupd(m2, n2, d2, sp * gs, sp);
                oupd(m3, n3, d3, sn * gs, sn);
            }
        }
    }

    // merge the 8 row-groups within each wave (states replicated across 8 lanes)
#pragma unroll
    for (int off = 8; off <= 32; off <<= 1) {
        shfl_merge(m0, n0, d0, off);
        shfl_merge(m1, n1, d1, off);
        shfl_merge(m2, n2, d2, off);
        shfl_merge(m3, n3, d3, off);
    }
    if (lane == 0) {
        float* r = s_red + wave * 12;
        r[0]=m0; r[1]=n0; r[2]=d0;
        r[3]=m1; r[4]=n1; r[5]=d1;
        r[6]=m2; r[7]=n2; r[8]=d2;
        r[9]=m3; r[10]=n3; r[11]=d3;
    }
    __syncthreads();

    if (tid == 0) {
        float M0=s_red[0], N0=s_red[1], D0=s_red[2];
        float M1=s_red[3], N1=s_red[4], D1=s_red[5];
        float M2=s_red[6], N2=s_red[7], D2=s_red[8];
        float M3=s_red[9], N3=s_red[10], D3=s_red[11];
#pragma unroll
        for (int w = 1; w < NWAVE; ++w) {
            const float* r = s_red + w * 12;
            omerge(M0, N0, D0, r[0], r[1], r[2]);
            omerge(M1, N1, D1, r[3], r[4], r[5]);
            omerge(M2, N2, D2, r[6], r[7], r[8]);
            omerge(M3, N3, D3, r[9], r[10], r[11]);
        }
        const float cgx = N0 / D0, cgy = N1 / D1;
        const float cex = N2 / D2, cey = N3 / D3;
        out[b]      = lam * cgx + (1.f - lam) * cex;
        out[NB + b] = lam * cgy + (1.f - lam) * cey;
        if (b == 0) {
            out[2 * NB]     = lam;
            out[2 * NB + 1] = tau_g;
            out[2 * NB + 2] = tau_e;
        }
    }
}

extern "C" void kernel_launch(void* const* d_in, const int* in_sizes, int n_in,
                              void* d_out, int out_size, void* d_ws, size_t ws_size,
                              hipStream_t stream) {
    const int* items_long  = (const int*)d_in[0];
    const int* dts_long    = (const int*)d_in[1];
    const int* items_short = (const int*)d_in[3];
    const int* dts_short   = (const int*)d_in[4];
    const int* pos_items   = (const int*)d_in[6];
    const int* neg_items   = (const int*)d_in[7];
    const float* emb       = (const float*)d_in[8];
    const float* gate_g    = (const float*)d_in[9];
    const float* gate_e    = (const float*)d_in[10];
    const float* raw_tau_g = (const float*)d_in[11];
    const float* raw_tau_e = (const float*)d_in[12];
    const float* fuse      = (const float*)d_in[13];
    float* out = (float*)d_out;

    if (ws_size >= TABLE_BYTES) {
        const ushort_t* tabh = (const ushort_t*)d_ws;
        cvt_kernel<<<TABLE_ELEMS / 8 / 256, 256, 0, stream>>>(emb, (uint4*)d_ws);
        lic_kernel<true><<<NB, BLOCK, 0, stream>>>(
            items_long, dts_long, items_short, dts_short,
            pos_items, neg_items, emb, tabh, gate_g, gate_e,
            raw_tau_g, raw_tau_e, fuse, out);
    } else {
        lic_kernel<false><<<NB, BLOCK, 0, stream>>>(
            items_long, dts_long, items_short, dts_short,
            pos_items, neg_items, emb, (const ushort_t*)nullptr, gate_g, gate_e,
            raw_tau_g, raw_tau_e, fuse, out);
    }
}

// Round 10
// 127.073 us; speedup vs baseline: 1.4967x; 1.0037x over previous
//
#include <hip/hip_runtime.h>
#include <hip/hip_bf16.h>

#define NB 2048
#define LL 512
#define LS 64
#define LT (LL + LS)   // 576 rows per batch
#define D 64
#define BLOCK 256
#define NWAVE 4
#define NIT (LT / 32)  // 18 row-groups of 32 per block
#define NUM_ITEMS 100000
#define TABLE_ELEMS (NUM_ITEMS * D)           // 6,400,000
#define TABLE_BYTES ((size_t)TABLE_ELEMS * 2) // 12.8 MB as bf16

typedef unsigned short ushort_t;

__device__ __forceinline__ float u2f(unsigned int bits) {
    union { unsigned int i; float f; } c; c.i = bits; return c.f;
}

__device__ __forceinline__ ushort_t f2bf(float f) {
    union { float f; unsigned int u; } c; c.f = f;
    unsigned int u = c.u;
    unsigned int r = (u + 0x7fffu + ((u >> 16) & 1u)) >> 16;   // RTNE
    return (ushort_t)r;
}

__device__ __forceinline__ unsigned int pack2(float lo, float hi) {
    return (unsigned int)f2bf(lo) | ((unsigned int)f2bf(hi) << 16);
}

// fp32 emb -> bf16 table (one uint4 = 8 bf16 per thread)
__global__ void __launch_bounds__(256) cvt_kernel(const float* __restrict__ emb,
                                                  uint4* __restrict__ dst)
{
    const size_t i = (size_t)blockIdx.x * 256 + threadIdx.x;   // < TABLE_ELEMS/8
    const float4* src = (const float4*)emb + 2 * i;
    const float4 a = src[0];
    const float4 b = src[1];
    uint4 r;
    r.x = pack2(a.x, a.y);
    r.y = pack2(a.z, a.w);
    r.z = pack2(b.x, b.y);
    r.w = pack2(b.z, b.w);
    dst[i] = r;
}

// 8 named scalars — no arrays, no dynamic indexing, SROA-proof.
struct F8 { float a, b, c, d, e, f, g, h; };

__device__ __forceinline__ F8 unpack8(uint4 u) {
    F8 r;
    r.a = u2f(u.x << 16); r.b = u2f(u.x & 0xffff0000u);
    r.c = u2f(u.y << 16); r.d = u2f(u.y & 0xffff0000u);
    r.e = u2f(u.z << 16); r.f = u2f(u.z & 0xffff0000u);
    r.g = u2f(u.w << 16); r.h = u2f(u.w & 0xffff0000u);
    return r;
}

// dual dot-product: sp = k.qp, sn = k.qn (straight-line, 16 fma)
__device__ __forceinline__ void dot2(const F8& k, const F8& qp, const F8& qn,
                                     float& sp, float& sn) {
    sp = k.a * qp.a;            sn = k.a * qn.a;
    sp = fmaf(k.b, qp.b, sp);   sn = fmaf(k.b, qn.b, sn);
    sp = fmaf(k.c, qp.c, sp);   sn = fmaf(k.c, qn.c, sn);
    sp = fmaf(k.d, qp.d, sp);   sn = fmaf(k.d, qn.d, sn);
    sp = fmaf(k.e, qp.e, sp);   sn = fmaf(k.e, qn.e, sn);
    sp = fmaf(k.f, qp.f, sp);   sn = fmaf(k.f, qn.f, sn);
    sp = fmaf(k.g, qp.g, sp);   sn = fmaf(k.g, qn.g, sn);
    sp = fmaf(k.h, qp.h, sp);   sn = fmaf(k.h, qn.h, sn);
}

__device__ __forceinline__ float softplus_f(float x) {
    return fmaxf(x, 0.f) + log1pf(expf(-fabsf(x)));
}

// Online-softmax: add one element (logit, weight=sim) to state (m, n, d)
__device__ __forceinline__ void oupd(float& m, float& n, float& d,
                                     float logit, float sim) {
    float M = fmaxf(m, logit);
    float a = __expf(m - M);        // 0 when m = -1e30
    float e = __expf(logit - M);
    n = fmaf(n, a, e * sim);
    d = fmaf(d, a, e);
    m = M;
}

__device__ __forceinline__ void omerge(float& m, float& n, float& d,
                                       float m2, float n2, float d2) {
    float M = fmaxf(m, m2);
    float a = __expf(m - M), bb = __expf(m2 - M);
    n = n * a + n2 * bb;
    d = d * a + d2 * bb;
    m = M;
}

__device__ __forceinline__ void shfl_merge(float& m, float& n, float& d, int off) {
    float m2 = __shfl_xor(m, off);
    float n2 = __shfl_xor(n, off);
    float d2 = __shfl_xor(d, off);
    omerge(m, n, d, m2, n2, d2);
}

template <bool USE_BF16>
__global__ void __launch_bounds__(BLOCK, 4) lic_kernel(   // 4 waves/EU -> 128 VGPR cap
    const int* __restrict__ items_long, const int* __restrict__ dts_long,
    const int* __restrict__ items_short, const int* __restrict__ dts_short,
    const int* __restrict__ pos_items, const int* __restrict__ neg_items,
    const float* __restrict__ emb, const ushort_t* __restrict__ tabh,
    const float* __restrict__ gate_g, const float* __restrict__ gate_e,
    const float* __restrict__ raw_tau_g, const float* __restrict__ raw_tau_e,
    const float* __restrict__ fuse_logits,
    float* __restrict__ out)
{
    __shared__ int   s_items[LT];
    __shared__ float s_gate[LT];          // gate * inv_tau (pre-scaled)
    __shared__ float s_red[NWAVE * 12];

    const int b = blockIdx.x;
    const int tid = threadIdx.x;
    const int lane = tid & 63;
    const int wave = tid >> 6;
    const int sub = lane & 7;        // 16B chunk within row
    const int rloc = lane >> 3;      // row-group within wave

    const float tau_g = softplus_f(raw_tau_g[0]) + 1e-6f;
    const float tau_e = softplus_f(raw_tau_e[0]) + 1e-6f;
    const float inv_tau_g = 1.f / tau_g;
    const float inv_tau_e = 1.f / tau_e;
    const float lam = 1.f / (1.f + expf(fuse_logits[1] - fuse_logits[0]));

    // ---- stage all 576 indices + prescaled gates into LDS (coalesced) ----
    {
        int2 it = ((const int2*)(items_long + (size_t)b * LL))[tid];
        int2 dt = ((const int2*)(dts_long  + (size_t)b * LL))[tid];
        s_items[2 * tid]     = it.x;
        s_items[2 * tid + 1] = it.y;
        s_gate[2 * tid]      = gate_g[dt.x] * inv_tau_g;   // 512B table: L1-resident
        s_gate[2 * tid + 1]  = gate_g[dt.y] * inv_tau_g;
        if (tid < LS / 2) {
            int2 its = ((const int2*)(items_short + (size_t)b * LS))[tid];
            int2 dts = ((const int2*)(dts_short  + (size_t)b * LS))[tid];
            s_items[LL + 2 * tid]     = its.x;
            s_items[LL + 2 * tid + 1] = its.y;
            s_gate[LL + 2 * tid]      = gate_e[dts.x] * inv_tau_e;
            s_gate[LL + 2 * tid + 1]  = gate_e[dts.y] * inv_tau_e;
        }
    }

    // q fragments (fp32): lane holds elements [sub*8, sub*8+8)
    F8 qp, qn;
    {
        const int pi = pos_items[b];
        const int ni = neg_items[b];
        const float* pp = emb + (size_t)pi * D + sub * 8;
        const float* pn = emb + (size_t)ni * D + sub * 8;
        float4 a0 = *(const float4*)(pp);
        float4 a1 = *(const float4*)(pp + 4);
        float4 b0 = *(const float4*)(pn);
        float4 b1 = *(const float4*)(pn + 4);
        qp.a=a0.x; qp.b=a0.y; qp.c=a0.z; qp.d=a0.w;
        qp.e=a1.x; qp.f=a1.y; qp.g=a1.z; qp.h=a1.w;
        qn.a=b0.x; qn.b=b0.y; qn.c=b0.z; qn.d=b0.w;
        qn.e=b1.x; qn.f=b1.y; qn.g=b1.z; qn.h=b1.w;
    }
    __syncthreads();   // staging complete

    // online-softmax states: 0=long/pos 1=long/neg 2=short/pos 3=short/neg
    float m0=-1e30f, n0=0.f, d0=0.f;
    float m1=-1e30f, n1=0.f, d1=0.f;
    float m2=-1e30f, n2=0.f, d2=0.f;
    float m3=-1e30f, n3=0.f, d3=0.f;

    const int start = wave * 8 + rloc;   // 0..31; rows: start + 32*i

    if (USE_BF16) {
        const uint4* __restrict__ tab = (const uint4*)tabh;

#define CONSUME(I, U)                                                        \
        do {                                                                 \
            F8 k = unpack8(U);                                               \
            float sp, sn;                                                    \
            dot2(k, qp, qn, sp, sn);                                         \
            sp += __shfl_xor(sp, 1); sn += __shfl_xor(sn, 1);                \
            sp += __shfl_xor(sp, 2); sn += __shfl_xor(sn, 2);                \
            sp += __shfl_xor(sp, 4); sn += __shfl_xor(sn, 4);                \
            const float gs = s_gate[start + 32 * (I)];                       \
            if ((I) < 16) {                                                  \
                oupd(m0, n0, d0, sp * gs, sp);                               \
                oupd(m1, n1, d1, sn * gs, sn);                               \
            } else {                                                         \
                oupd(m2, n2, d2, sp * gs, sp);                               \
                oupd(m3, n3, d3, sn * gs, sn);                               \
            }                                                                \
        } while (0)

#define LD(I) tab[(size_t)s_items[start + 32 * (I)] * 8 + sub]

        // 8-deep software pipeline: 8 independent row-gathers in flight/wave
        uint4 A0 = LD(0);
        uint4 A1 = LD(1);
        uint4 A2 = LD(2);
        uint4 A3 = LD(3);
        uint4 A4 = LD(4);
        uint4 A5 = LD(5);
        uint4 A6 = LD(6);
        uint4 A7 = LD(7);

        CONSUME(0, A0);  A0 = LD(8);
        CONSUME(1, A1);  A1 = LD(9);
        CONSUME(2, A2);  A2 = LD(10);
        CONSUME(3, A3);  A3 = LD(11);
        CONSUME(4, A4);  A4 = LD(12);
        CONSUME(5, A5);  A5 = LD(13);
        CONSUME(6, A6);  A6 = LD(14);
        CONSUME(7, A7);  A7 = LD(15);
        CONSUME(8, A0);  A0 = LD(16);
        CONSUME(9, A1);  A1 = LD(17);
        CONSUME(10, A2);
        CONSUME(11, A3);
        CONSUME(12, A4);
        CONSUME(13, A5);
        CONSUME(14, A6);
        CONSUME(15, A7);
        CONSUME(16, A0);
        CONSUME(17, A1);
#undef LD
#undef CONSUME
    } else {
        // fp32 fallback (ws too small) — simple loop, struct-scalar body
        for (int i = 0; i < NIT; ++i) {
            const int row = start + 32 * i;
            const float* rp = emb + (size_t)s_items[row] * D + sub * 8;
            const float4 u0 = *(const float4*)(rp);
            const float4 u1 = *(const float4*)(rp + 4);
            F8 k;
            k.a=u0.x; k.b=u0.y; k.c=u0.z; k.d=u0.w;
            k.e=u1.x; k.f=u1.y; k.g=u1.z; k.h=u1.w;
            float sp, sn;
            dot2(k, qp, qn, sp, sn);
            sp += __shfl_xor(sp, 1); sn += __shfl_xor(sn, 1);
            sp += __shfl_xor(sp, 2); sn += __shfl_xor(sn, 2);
            sp += __shfl_xor(sp, 4); sn += __shfl_xor(sn, 4);
            const float gs = s_gate[row];
            if (row < LL) {
                oupd(m0, n0, d0, sp * gs, sp);
                oupd(m1, n1, d1, sn * gs, sn);
            } else {
                oupd(m2, n2, d2, sp * gs, sp);
                oupd(m3, n3, d3, sn * gs, sn);
            }
        }
    }

    // merge the 8 row-groups within each wave (states replicated across 8 lanes)
#pragma unroll
    for (int off = 8; off <= 32; off <<= 1) {
        shfl_merge(m0, n0, d0, off);
        shfl_merge(m1, n1, d1, off);
        shfl_merge(m2, n2, d2, off);
        shfl_merge(m3, n3, d3, off);
    }
    if (lane == 0) {
        float* r = s_red + wave * 12;
        r[0]=m0; r[1]=n0; r[2]=d0;
        r[3]=m1; r[4]=n1; r[5]=d1;
        r[6]=m2; r[7]=n2; r[8]=d2;
        r[9]=m3; r[10]=n3; r[11]=d3;
    }
    __syncthreads();

    if (tid == 0) {
        float M0=s_red[0], N0=s_red[1], D0=s_red[2];
        float M1=s_red[3], N1=s_red[4], D1=s_red[5];
        float M2=s_red[6], N2=s_red[7], D2=s_red[8];
        float M3=s_red[9], N3=s_red[10], D3=s_red[11];
#pragma unroll
        for (int w = 1; w < NWAVE; ++w) {
            const float* r = s_red + w * 12;
            omerge(M0, N0, D0, r[0], r[1], r[2]);
            omerge(M1, N1, D1, r[3], r[4], r[5]);
            omerge(M2, N2, D2, r[6], r[7], r[8]);
            omerge(M3, N3, D3, r[9], r[10], r[11]);
        }
        const float cgx = N0 / D0, cgy = N1 / D1;
        const float cex = N2 / D2, cey = N3 / D3;
        out[b]      = lam * cgx + (1.f - lam) * cex;
        out[NB + b] = lam * cgy + (1.f - lam) * cey;
        if (b == 0) {
            out[2 * NB]     = lam;
            out[2 * NB + 1] = tau_g;
            out[2 * NB + 2] = tau_e;
        }
    }
}

extern "C" void kernel_launch(void* const* d_in, const int* in_sizes, int n_in,
                              void* d_out, int out_size, void* d_ws, size_t ws_size,
                              hipStream_t stream) {
    const int* items_long  = (const int*)d_in[0];
    const int* dts_long    = (const int*)d_in[1];
    const int* items_short = (const int*)d_in[3];
    const int* dts_short   = (const int*)d_in[4];
    const int* pos_items   = (const int*)d_in[6];
    const int* neg_items   = (const int*)d_in[7];
    const float* emb       = (const float*)d_in[8];
    const float* gate_g    = (const float*)d_in[9];
    const float* gate_e    = (const float*)d_in[10];
    const float* raw_tau_g = (const float*)d_in[11];
    const float* raw_tau_e = (const float*)d_in[12];
    const float* fuse      = (const float*)d_in[13];
    float* out = (float*)d_out;

    if (ws_size >= TABLE_BYTES) {
        const ushort_t* tabh = (const ushort_t*)d_ws;
        cvt_kernel<<<TABLE_ELEMS / 8 / 256, 256, 0, stream>>>(emb, (uint4*)d_ws);
        lic_kernel<true><<<NB, BLOCK, 0, stream>>>(
            items_long, dts_long, items_short, dts_short,
            pos_items, neg_items, emb, tabh, gate_g, gate_e,
            raw_tau_g, raw_tau_e, fuse, out);
    } else {
        lic_kernel<false><<<NB, BLOCK, 0, stream>>>(
            items_long, dts_long, items_short, dts_short,
            pos_items, neg_items, emb, (const ushort_t*)nullptr, gate_g, gate_e,
            raw_tau_g, raw_tau_e, fuse, out);
    }
}